// Round 2
// baseline (1881.374 us; speedup 1.0000x reference)
//
#include <hip/hip_runtime.h>
#include <math.h>

// ---------------- problem constants ----------------
#define BB    32
#define C_IN  3
#define H0    256
#define W0    256
#define C1    32          // conv1 out: (B,32,128,128)
#define H1    128
#define W1    128
#define C2    64          // conv2 out: (B,64,64,64)
#define H2    64
#define W2    64
#define HW2   (H2*W2)     // 4096
#define N_EMB 512
#define E_DIM 64

// ---------------- conv1: 3->32, k4 s2 p1, ReLU ----------------
__global__ __launch_bounds__(256) void conv1_kernel(const float* __restrict__ x,
        const float* __restrict__ w, const float* __restrict__ bias,
        float* __restrict__ out) {
    int t = blockIdx.x * 256 + threadIdx.x;           // G*128*128 threads
    int ox = t & (W1 - 1);
    int oy = (t >> 7) & (H1 - 1);
    int b  = t >> 14;
    const float* xb = x + (size_t)b * (C_IN * H0 * W0);
    float v[48];
    #pragma unroll
    for (int ic = 0; ic < 3; ++ic)
        #pragma unroll
        for (int dy = 0; dy < 4; ++dy) {
            int iy = oy * 2 - 1 + dy;
            #pragma unroll
            for (int dx = 0; dx < 4; ++dx) {
                int ix = ox * 2 - 1 + dx;
                float val = 0.f;
                if ((unsigned)iy < H0 && (unsigned)ix < W0)
                    val = xb[((size_t)ic * H0 + iy) * W0 + ix];
                v[(ic * 4 + dy) * 4 + dx] = val;
            }
        }
    float* ob = out + (size_t)b * (C1 * H1 * W1) + (size_t)oy * W1 + ox;
    #pragma unroll
    for (int oc = 0; oc < C1; ++oc) {
        float a = bias[oc];
        #pragma unroll
        for (int k = 0; k < 48; ++k) a = fmaf(v[k], w[oc * 48 + k], a);
        ob[(size_t)oc * (H1 * W1)] = fmaxf(a, 0.f);
    }
}

// ---------------- conv2: 32->64, k4 s2 p1, ReLU ----------------
__global__ __launch_bounds__(256) void conv2_kernel(const float* __restrict__ in,
        const float* __restrict__ w, const float* __restrict__ bias,
        float* __restrict__ out) {
    int t = blockIdx.x * 256 + threadIdx.x;           // G*64*64 threads
    int ox = t & (W2 - 1);
    int oy = (t >> 6) & (H2 - 1);
    int b  = t >> 12;
    float acc[64];
    #pragma unroll
    for (int oc = 0; oc < 64; ++oc) acc[oc] = bias[oc];
    const float* ib = in + (size_t)b * (C1 * H1 * W1);
    for (int ic = 0; ic < 32; ++ic) {
        float v[16];
        #pragma unroll
        for (int dy = 0; dy < 4; ++dy) {
            int iy = oy * 2 - 1 + dy;
            #pragma unroll
            for (int dx = 0; dx < 4; ++dx) {
                int ix = ox * 2 - 1 + dx;
                float val = 0.f;
                if ((unsigned)iy < H1 && (unsigned)ix < W1)
                    val = ib[((size_t)ic * H1 + iy) * W1 + ix];
                v[dy * 4 + dx] = val;
            }
        }
        #pragma unroll
        for (int oc = 0; oc < 64; ++oc) {
            const float* wp = w + ((size_t)oc * 32 + ic) * 16;
            float a = acc[oc];
            #pragma unroll
            for (int k = 0; k < 16; ++k) a = fmaf(v[k], wp[k], a);
            acc[oc] = a;
        }
    }
    float* ob = out + (size_t)b * (C2 * HW2) + (size_t)oy * W2 + ox;
    #pragma unroll
    for (int oc = 0; oc < 64; ++oc) ob[(size_t)oc * HW2] = fmaxf(acc[oc], 0.f);
}

// ---------------- embedding squared norms ----------------
__global__ void e2_kernel(const float* __restrict__ emb, float* __restrict__ e2) {
    int e = blockIdx.x * 64 + threadIdx.x;            // 512 total
    float s = 0.f;
    #pragma unroll
    for (int c = 0; c < E_DIM; ++c) {
        float v = emb[(size_t)e * E_DIM + c];
        s = fmaf(v, v, s);
    }
    e2[e] = s;
}

// ---------------- VQ: argmin(|e|^2 - 2 z.e), gather -> q ----------------
__global__ __launch_bounds__(256) void vq_kernel(const float* __restrict__ z,
        const float* __restrict__ emb, const float* __restrict__ e2,
        float* __restrict__ q) {
    __shared__ float se[128 * 64 + 128];              // emb chunk + |e|^2 chunk
    int r  = blockIdx.x * 256 + threadIdx.x;          // vector id within group
    int hw = r & (HW2 - 1);
    int b  = r >> 12;
    const float* zp = z + (size_t)b * C2 * HW2 + hw;
    float zv[64];
    #pragma unroll
    for (int c = 0; c < 64; ++c) zv[c] = zp[(size_t)c * HW2];   // coalesced per c

    float best = 3.4e38f;
    int bi = 0;
    for (int c0 = 0; c0 < N_EMB; c0 += 128) {
        __syncthreads();
        #pragma unroll
        for (int i = 0; i < 32; ++i)                  // 8192 floats, coalesced
            se[threadIdx.x + i * 256] = emb[(size_t)c0 * 64 + threadIdx.x + i * 256];
        if (threadIdx.x < 128) se[8192 + threadIdx.x] = e2[c0 + threadIdx.x];
        __syncthreads();
        for (int e = 0; e < 128; ++e) {
            const float4* ep = (const float4*)(se + e * 64);
            float d0 = 0.f, d1 = 0.f, d2 = 0.f, d3 = 0.f;
            #pragma unroll
            for (int k = 0; k < 16; ++k) {
                float4 ev = ep[k];
                d0 = fmaf(zv[4 * k + 0], ev.x, d0);
                d1 = fmaf(zv[4 * k + 1], ev.y, d1);
                d2 = fmaf(zv[4 * k + 2], ev.z, d2);
                d3 = fmaf(zv[4 * k + 3], ev.w, d3);
            }
            float score = se[8192 + e] - 2.f * ((d0 + d1) + (d2 + d3));
            if (score < best) { best = score; bi = c0 + e; }
        }
    }
    // gather chosen embedding -> q. NOTE: q is only 4-byte aligned (output
    // layout puts it at +6291457 floats) — scalar stores only, no float4.
    const float4* er = (const float4*)(emb + (size_t)bi * E_DIM);
    float* qp = q + (size_t)r * E_DIM;
    #pragma unroll
    for (int k = 0; k < 16; ++k) {
        float4 ev = er[k];
        qp[4 * k + 0] = ev.x;
        qp[4 * k + 1] = ev.y;
        qp[4 * k + 2] = ev.z;
        qp[4 * k + 3] = ev.w;
    }
}

// ---------------- loss = 1.25 * mean((q_flat - z_flat)^2) ----------------
__global__ __launch_bounds__(256) void loss_partial(const float* __restrict__ q,
        const float* __restrict__ z, float* __restrict__ part, int n) {
    float s = 0.f;
    int stride = gridDim.x * 256;
    for (int i = blockIdx.x * 256 + threadIdx.x; i < n; i += stride) {
        float d = q[i] - z[i];
        s = fmaf(d, d, s);
    }
    #pragma unroll
    for (int off = 32; off; off >>= 1) s += __shfl_down(s, off, 64);
    __shared__ float red[4];
    int lane = threadIdx.x & 63, wid = threadIdx.x >> 6;
    if (lane == 0) red[wid] = s;
    __syncthreads();
    if (threadIdx.x == 0) part[blockIdx.x] = (red[0] + red[1]) + (red[2] + red[3]);
}

__global__ __launch_bounds__(256) void loss_final(const float* __restrict__ part,
        float* __restrict__ loss, float scale) {
    float s = 0.f;
    for (int i = threadIdx.x; i < 2048; i += 256) s += part[i];
    #pragma unroll
    for (int off = 32; off; off >>= 1) s += __shfl_down(s, off, 64);
    __shared__ float red[4];
    int lane = threadIdx.x & 63, wid = threadIdx.x >> 6;
    if (lane == 0) red[wid] = s;
    __syncthreads();
    if (threadIdx.x == 0)
        *loss = ((red[0] + red[1]) + (red[2] + red[3])) * scale;
}

// ---- transpose ConvTranspose weights: (CI,CO,4,4) -> [cls][ic][tap][oc] ----
template<int CI, int CO>
__global__ void transpose_deconv_w(const float* __restrict__ w, float* __restrict__ wt) {
    int i = blockIdx.x * 256 + threadIdx.x;
    if (i >= 4 * CI * 4 * CO) return;
    int oc  = i % CO;
    int tap = (i / CO) % 4;
    int ic  = (i / (CO * 4)) % CI;
    int cls = i / (CO * 4 * CI);
    int py = cls >> 1, px = cls & 1, ty = tap >> 1, tx = tap & 1;
    int ky = py ? (ty ? 0 : 2) : (ty ? 3 : 1);
    int kx = px ? (tx ? 0 : 2) : (tx ? 3 : 1);
    wt[i] = w[(((size_t)ic * CO + oc) * 4 + ky) * 4 + kx];
}

// ---- ConvTranspose k4 s2 p1 as 4 parity-class 2x2 convs, ReLU ----
template<int CI, int CO, int HI, int WI>
__global__ __launch_bounds__(256) void deconv_kernel(const float* __restrict__ in,
        const float* __restrict__ wt, const float* __restrict__ bias,
        float* __restrict__ out) {
    int cls = blockIdx.y;
    int py = cls >> 1, px = cls & 1;
    int t = blockIdx.x * 256 + threadIdx.x;           // G*HI*WI threads
    int x = t % WI;
    int y = (t / WI) % HI;
    int b = t / (WI * HI);
    int iy1 = y + (py ? 1 : -1);
    int ix1 = x + (px ? 1 : -1);
    bool vy1 = (unsigned)iy1 < HI, vx1 = (unsigned)ix1 < WI;
    float acc[CO];
    #pragma unroll
    for (int oc = 0; oc < CO; ++oc) acc[oc] = bias[oc];
    const float* ib = in + (size_t)b * CI * HI * WI;
    for (int ic = 0; ic < CI; ++ic) {
        const float* p = ib + (size_t)ic * HI * WI;
        float v0 = p[y * WI + x];
        float v1 = vx1 ? p[y * WI + ix1] : 0.f;
        float v2 = vy1 ? p[iy1 * WI + x] : 0.f;
        float v3 = (vy1 && vx1) ? p[iy1 * WI + ix1] : 0.f;
        const float* wp = wt + (((size_t)cls * CI + ic) * 4) * CO;
        #pragma unroll
        for (int oc = 0; oc < CO; ++oc) {
            float a = acc[oc];
            a = fmaf(v0, wp[oc], a);
            a = fmaf(v1, wp[CO + oc], a);
            a = fmaf(v2, wp[2 * CO + oc], a);
            a = fmaf(v3, wp[3 * CO + oc], a);
            acc[oc] = a;
        }
    }
    int oy = 2 * y + py, ox = 2 * x + px;
    float* ob = out + (size_t)b * CO * (4 * HI * WI) + (size_t)oy * (2 * WI) + ox;
    #pragma unroll
    for (int oc = 0; oc < CO; ++oc)
        ob[(size_t)oc * (4 * HI * WI)] = fmaxf(acc[oc], 0.f);
}

// ---------------- conv3: 32->3, k3 s1 p1, sigmoid ----------------
__global__ __launch_bounds__(256) void conv3_kernel(const float* __restrict__ in,
        const float* __restrict__ w, const float* __restrict__ bias,
        float* __restrict__ out) {
    int t = blockIdx.x * 256 + threadIdx.x;           // G*256*256 threads
    int ox = t & (W0 - 1);
    int oy = (t >> 8) & (H0 - 1);
    int b  = t >> 16;
    float a0 = bias[0], a1 = bias[1], a2 = bias[2];
    const float* ib = in + (size_t)b * (32 * H0 * W0);
    for (int ic = 0; ic < 32; ++ic) {
        const float* p = ib + (size_t)ic * (H0 * W0);
        float v[9];
        #pragma unroll
        for (int dy = 0; dy < 3; ++dy) {
            int iy = oy - 1 + dy;
            #pragma unroll
            for (int dx = 0; dx < 3; ++dx) {
                int ix = ox - 1 + dx;
                v[dy * 3 + dx] = ((unsigned)iy < H0 && (unsigned)ix < W0)
                                 ? p[(size_t)iy * W0 + ix] : 0.f;
            }
        }
        #pragma unroll
        for (int k = 0; k < 9; ++k) {
            a0 = fmaf(v[k], w[(0 * 32 + ic) * 9 + k], a0);
            a1 = fmaf(v[k], w[(1 * 32 + ic) * 9 + k], a1);
            a2 = fmaf(v[k], w[(2 * 32 + ic) * 9 + k], a2);
        }
    }
    float* ob = out + (size_t)b * (3 * H0 * W0) + (size_t)oy * W0 + ox;
    ob[0]                      = 1.f / (1.f + expf(-a0));
    ob[(size_t)1 * H0 * W0]    = 1.f / (1.f + expf(-a1));
    ob[(size_t)2 * H0 * W0]    = 1.f / (1.f + expf(-a2));
}

// ---------------- launch ----------------
extern "C" void kernel_launch(void* const* d_in, const int* in_sizes, int n_in,
                              void* d_out, int out_size, void* d_ws, size_t ws_size,
                              hipStream_t stream) {
    (void)in_sizes; (void)n_in; (void)out_size;
    const float* x   = (const float*)d_in[0];
    const float* e1w = (const float*)d_in[1];
    const float* e1b = (const float*)d_in[2];
    const float* e2w = (const float*)d_in[3];
    const float* e2b = (const float*)d_in[4];
    const float* emb = (const float*)d_in[5];
    const float* d1w = (const float*)d_in[6];
    const float* d1b = (const float*)d_in[7];
    const float* d2w = (const float*)d_in[8];
    const float* d2b = (const float*)d_in[9];
    const float* d3w = (const float*)d_in[10];
    const float* d3b = (const float*)d_in[11];

    float* out   = (float*)d_out;
    float* recon = out;                    // 6291456 floats
    float* loss  = out + 6291456;          // 1 float
    float* q     = out + 6291457;          // 8388608 floats (only 4B-aligned!)

    // ---- workspace layout (floats) ----
    float* ws  = (float*)d_ws;
    float* wt1 = ws;                       // 65536
    float* wt2 = ws + 65536;               // 32768
    float* e2v = ws + 98304;               // 512
    float* prt = ws + 98816;               // 2048 (always fully written)
    float* big = ws + 100864;              // shared big region

    // choose batch-group size G so peak footprint fits ws_size
    size_t wsf  = ws_size / sizeof(float);
    size_t bigf = (wsf > 100864) ? wsf - 100864 : 0;
    int G = 32;
    while (G > 1 && (size_t)G * 3145728 > bigf) G >>= 1;  // decoder peak: G*(h1+h2)
    int ngrp = BB / G;

    transpose_deconv_w<64, 64><<<256, 256, 0, stream>>>(d1w, wt1);
    transpose_deconv_w<64, 32><<<128, 256, 0, stream>>>(d2w, wt2);
    e2_kernel<<<8, 64, 0, stream>>>(emb, e2v);

    for (int g = 0; g < ngrp; ++g) {
        const float* xg = x + (size_t)g * G * (C_IN * H0 * W0);
        float* z1g = big;                              // G*524288
        float* zg  = big + (size_t)G * 524288;         // G*262144
        float* qg  = q + (size_t)g * G * 262144;

        conv1_kernel<<<64 * G, 256, 0, stream>>>(xg, e1w, e1b, z1g);
        conv2_kernel<<<16 * G, 256, 0, stream>>>(z1g, e2w, e2b, zg);
        vq_kernel<<<16 * G, 256, 0, stream>>>(zg, emb, e2v, qg);
        loss_partial<<<64 * G, 256, 0, stream>>>(qg, zg, prt + g * 64 * G,
                                                 G * 262144);

        // decoder reuses big region (z1g/zg dead now; qg lives in d_out)
        float* h1g = big;                              // G*1048576
        float* h2g = big + (size_t)G * 1048576;        // G*2097152
        deconv_kernel<64, 64, 64, 64>
            <<<dim3(16 * G, 4), 256, 0, stream>>>(qg, wt1, d1b, h1g);
        deconv_kernel<64, 32, 128, 128>
            <<<dim3(64 * G, 4), 256, 0, stream>>>(h1g, wt2, d2b, h2g);
        conv3_kernel<<<256 * G, 256, 0, stream>>>(h2g, d3w, d3b,
                                                  recon + (size_t)g * G * 196608);
    }
    loss_final<<<1, 256, 0, stream>>>(prt, loss, 1.25f / (float)(BB * C2 * HW2));
}